// Round 2
// baseline (249.775 us; speedup 1.0000x reference)
//
#include <hip/hip_runtime.h>
#include <hip/hip_bf16.h>

// 2-layer GCN (PyG GCNConv) on MI355X.
// R20: bucket-fused backend. csrfill + agg1 + gemm2 merged into ONE kernel
// (k_bktagg): block = one 256-node bucket; colidx sorted into LDS (coalesced
// global dump kept for agg2), aggregation reads colidx from LDS, gemm2 MFMA
// tail runs per 128-node half (t1s 16.9KB -> 3 blocks/CU). Normalization now
// deg-based everywhere: partition counts deg[dst] via global atomics (dinv
// array gone; consumers do rsqrtf(deg+1) on TRANS pipe). k_part_gemm1 micro:
// src prefetched into regs in phase 1, x float4 loads issued before W scalar
// loads, LDS x-tile stride 66->68 words (aligned ds_read_b128 A-frags).
// Pipeline: memset -> [partition+deg | gemm1] -> [sort+agg1+gemm2] -> agg2.

#define IN_DIM 128
#define HID_DIM 64
#define OUT_DIM 32
#define BSHIFT 8
#define BSIZE 256
#define BMASK 255
#define PEB 8192      // edges per partition block
#define PTHREADS 512
#define CAPSHIFT 13   // 8192 slots per bucket segment (expected max ~4350)
#define COLCAP 5120   // LDS colidx capacity per bucket (expected max ~4350)

typedef __attribute__((ext_vector_type(2))) float v2f;
typedef __attribute__((ext_vector_type(8))) short short8v;
typedef __attribute__((ext_vector_type(4))) float float4v;

__device__ inline unsigned pack_bf16x2(float a, float b) {
    unsigned ua = __float_as_uint(a), ub = __float_as_uint(b);
    unsigned ra = (ua + 0x7fffu + ((ua >> 16) & 1u)) >> 16;        // RNE
    unsigned rb = (ub + 0x7fffu + ((ub >> 16) & 1u)) & 0xffff0000u;
    return (ra & 0xffffu) | rb;
}
__device__ inline unsigned short f2bf(float f) {
    unsigned u = __float_as_uint(f);
    return (unsigned short)((u + 0x7fffu + ((u >> 16) & 1u)) >> 16);
}
#define BF_LO(w) __uint_as_float((w) << 16)
#define BF_HI(w) __uint_as_float((w) & 0xffff0000u)

__device__ inline v2f bfpair(unsigned u) {
    v2f r;
    r.x = __uint_as_float(u << 16);
    r.y = __uint_as_float(u & 0xffff0000u);
    return r;
}
// scaled accumulate of a bf16x2 word
__device__ inline void accp(v2f& a, unsigned u, float dv) {
    a.x += BF_LO(u) * dv;
    a.y += BF_HI(u) * dv;
}

#define ACC8(q)                                         \
    do {                                                \
        acc[0] += BF_LO((q).x); acc[1] += BF_HI((q).x); \
        acc[2] += BF_LO((q).y); acc[3] += BF_HI((q).y); \
        acc[4] += BF_LO((q).z); acc[5] += BF_HI((q).z); \
        acc[6] += BF_LO((q).w); acc[7] += BF_HI((q).w); \
    } while (0)

// ---------------------------------------------------------------- K1: fused partition(+deg) + gemm1
__global__ __launch_bounds__(PTHREADS) void k_part_gemm1(
        const int* __restrict__ src, const int* __restrict__ dst, int E,
        int* __restrict__ bfill, int* __restrict__ deg,
        unsigned* __restrict__ packed, int B, int nPB,
        const float* __restrict__ x, const float* __restrict__ W,
        unsigned* __restrict__ g1b, int N) {
    __shared__ int cnt[512];
    __shared__ int off[512];
    __shared__ unsigned xs[32 * 68];  // 8.7 KB, stride 68 words (16B-aligned rows)
    int t = threadIdx.x;

    if (blockIdx.x < nPB) {
        // ---------------- partition body ----------------
        cnt[t] = 0;
        __syncthreads();
        int base = blockIdx.x * PEB;
        int dv[PEB / PTHREADS];
        int sv[PEB / PTHREADS];
#pragma unroll
        for (int i = 0; i < PEB / PTHREADS; ++i) {
            int e = base + i * PTHREADS + t;
            bool ok = e < E;
            dv[i] = ok ? dst[e] : -1;
            sv[i] = ok ? src[e] : 0;  // prefetch: kills phase-3 dependent load
            if (dv[i] >= 0) {
                atomicAdd(&cnt[dv[i] >> BSHIFT], 1);
                atomicAdd(&deg[dv[i]], 1);  // global degree (for rsqrt norm)
            }
        }
        __syncthreads();
        for (int b = t; b < B; b += PTHREADS) {
            int c = cnt[b];
            int o = c ? atomicAdd(&bfill[b], c) : 0;
            off[b] = (b << CAPSHIFT) + o;
        }
        __syncthreads();
#pragma unroll
        for (int i = 0; i < PEB / PTHREADS; ++i) {
            int d = dv[i];
            if (d >= 0) {
                int slot = atomicAdd(&off[d >> BSHIFT], 1);
                packed[slot] = ((unsigned)sv[i] << BSHIFT) | (unsigned)(d & BMASK);
            }
        }
    } else {
        // ---------------- gemm1 body: g1b = bf16(x @ W1), UNSCALED ----------------
        int row0 = (blockIdx.x - nPB) * 32;
        int w = t >> 6, lane = t & 63;
        int rg = w >> 2, wv = w & 3;  // row-group, col-wave
        int quad = lane >> 4, m = lane & 15;
        int ncol = wv * 16 + m;

        // x loads FIRST (HBM latency overlaps W fragment build)
        float4 xf[2];
#pragma unroll
        for (int i = 0; i < 2; ++i) {
            int idx = t + 512 * i;
            int r = idx >> 5, c4 = idx & 31;
            int grow = row0 + r;
            xf[i] = make_float4(0.f, 0.f, 0.f, 0.f);
            if (grow < N) xf[i] = ((const float4*)x)[(size_t)grow * 32 + c4];
        }

        // B-frags: bfrag[kt] element j = W[(kt*32 + quad*8 + j)*64 + ncol]
        union { unsigned u[4]; short8v s; } bf[4];
#pragma unroll
        for (int kt = 0; kt < 4; ++kt) {
#pragma unroll
            for (int jp = 0; jp < 4; ++jp) {
                int k0 = kt * 32 + quad * 8 + jp * 2;
                float f0 = W[(size_t)k0 * HID_DIM + ncol];
                float f1 = W[(size_t)(k0 + 1) * HID_DIM + ncol];
                bf[kt].u[jp] = pack_bf16x2(f0, f1);
            }
        }

        // stage x tile
#pragma unroll
        for (int i = 0; i < 2; ++i) {
            int idx = t + 512 * i;
            int r = idx >> 5, c4 = idx & 31;
            xs[r * 68 + c4 * 2]     = pack_bf16x2(xf[i].x, xf[i].y);
            xs[r * 68 + c4 * 2 + 1] = pack_bf16x2(xf[i].z, xf[i].w);
        }
        __syncthreads();

        float4v acc = {0.f, 0.f, 0.f, 0.f};
#pragma unroll
        for (int kt = 0; kt < 4; ++kt) {
            union { unsigned u[4]; short8v s; } af;
            const unsigned* ap = &xs[(rg * 16 + m) * 68 + kt * 16 + quad * 4];
            af.u[0] = ap[0]; af.u[1] = ap[1]; af.u[2] = ap[2]; af.u[3] = ap[3];
            acc = __builtin_amdgcn_mfma_f32_16x16x32_bf16(af.s, bf[kt].s, acc, 0, 0, 0);
        }

        unsigned short* g1s = (unsigned short*)g1b;
#pragma unroll
        for (int reg = 0; reg < 4; ++reg) {
            int r = row0 + rg * 16 + quad * 4 + reg;
            if (r < N) g1s[(size_t)r * HID_DIM + ncol] = f2bf(acc[reg]);
        }
    }
}

// ---------------------------------------------------------------- K2: bucket-fused sort + agg1 + gemm2
// block = one 256-node bucket, 512 threads = 8 waves.
// Phases: count -> scan (rowptr2) -> scatter colidx into LDS (+ coalesced
// global dump for agg2) -> per-half {aggregate 128 nodes -> t1s -> MFMA tail}.
__global__ __launch_bounds__(512) void k_bktagg(const unsigned* __restrict__ packed,
                                                const int* __restrict__ bfill,
                                                const unsigned* __restrict__ g1,
                                                const int* __restrict__ deg,
                                                const float* __restrict__ b1,
                                                const float* __restrict__ W2,
                                                int* __restrict__ colidx,
                                                uint2* __restrict__ rowptr2,
                                                unsigned short* __restrict__ g2s, int N) {
    __shared__ int ldeg[256];
    __shared__ int lscan[256];
    __shared__ int sexc[256];
    __shared__ int lfill[256];
    __shared__ int colL[COLCAP];        // 20 KB
    __shared__ unsigned t1s[128 * 33];  // 16.9 KB (per half)
    int t = threadIdx.x, bkt = blockIdx.x;
    int base = bkt << CAPSHIFT;
    int cnt = bfill[bkt];
    if (cnt > COLCAP) cnt = COLCAP;  // safety clamp (expected max ~4350)
    int end = base + cnt;

    // ---- phase 1: per-local-node count
    if (t < 256) ldeg[t] = 0;
    __syncthreads();
    for (int e = base + t; e < end; e += 512)
        atomicAdd(&ldeg[packed[e] & BMASK], 1);
    __syncthreads();

    // ---- phase 2: inclusive scan over 256 counts
    int v = (t < 256) ? ldeg[t] : 0;
    if (t < 256) lscan[t] = v;
    __syncthreads();
    for (int off = 1; off < 256; off <<= 1) {
        int xv = (t < 256 && t >= off) ? lscan[t - off] : 0;
        __syncthreads();
        if (t < 256) lscan[t] += xv;
        __syncthreads();
    }
    if (t < 256) {
        int exc = lscan[t] - v;
        sexc[t] = exc;
        lfill[t] = 0;
        int node = (bkt << BSHIFT) + t;
        if (node < N)
            rowptr2[node] = make_uint2((unsigned)(base + exc), (unsigned)(base + exc + v));
    }
    __syncthreads();

    // ---- phase 3: scatter into LDS colidx, then coalesced global dump
    for (int e = base + t; e < end; e += 512) {
        unsigned w = packed[e];
        int ld = w & BMASK;
        int pos = sexc[ld] + atomicAdd(&lfill[ld], 1);
        colL[pos] = (int)(w >> BSHIFT);
    }
    __syncthreads();
    for (int e = t; e < cnt; e += 512) colidx[base + e] = colL[e];

    // ---- phases 4+5, per 128-node half
    int qidx = t >> 4, ql = t & 15;         // 32 quarters
    int grp = ql >> 3, fp = ql & 7;
    int wave = t >> 6, lane = t & 63;
    int quad = lane >> 4, n16 = lane & 15;
    int cw = wave & 1;                      // gemm2 col tile of this wave
    int col = cw * 16 + n16;

    for (int half = 0; half < 2; ++half) {
        // phase 4: aggregate 4 nodes per quarter
        for (int i = 0; i < 4; ++i) {
            int lt = qidx * 4 + i;           // 0..127 (t1s row)
            int ln = half * 128 + lt;        // 0..255 (bucket-local node)
            int dd = (bkt << BSHIFT) + ln;
            int d = dd < N ? dd : N - 1;
            int eb = sexc[ln], ecnt = ldeg[ln];
            v2f a01 = {0.f, 0.f}, a23 = {0.f, 0.f}, a45 = {0.f, 0.f}, a67 = {0.f, 0.f};
            int e = eb, eend = eb + ecnt;
            for (; e + 4 <= eend; e += 4) {
                int s0 = colL[e + grp];
                int s1 = colL[e + 2 + grp];
                float dv0 = rsqrtf((float)deg[s0] + 1.0f);
                float dv1 = rsqrtf((float)deg[s1] + 1.0f);
                uint4 q0 = *(const uint4*)&g1[(size_t)s0 * 32 + fp * 4];
                uint4 q1 = *(const uint4*)&g1[(size_t)s1 * 32 + fp * 4];
                accp(a01, q0.x, dv0); accp(a23, q0.y, dv0);
                accp(a45, q0.z, dv0); accp(a67, q0.w, dv0);
                accp(a01, q1.x, dv1); accp(a23, q1.y, dv1);
                accp(a45, q1.z, dv1); accp(a67, q1.w, dv1);
            }
            for (; e + 2 <= eend; e += 2) {
                int s = colL[e + grp];
                float dvs = rsqrtf((float)deg[s] + 1.0f);
                uint4 qv = *(const uint4*)&g1[(size_t)s * 32 + fp * 4];
                accp(a01, qv.x, dvs); accp(a23, qv.y, dvs);
                accp(a45, qv.z, dvs); accp(a67, qv.w, dvs);
            }
            if (e < eend) {  // 1 edge left: grp 0 only
                int s = colL[e];
                float dvs = rsqrtf((float)deg[s] + 1.0f);
                uint4 qv = *(const uint4*)&g1[(size_t)s * 32 + fp * 4];
                if (grp == 0) {
                    accp(a01, qv.x, dvs); accp(a23, qv.y, dvs);
                    accp(a45, qv.z, dvs); accp(a67, qv.w, dvs);
                }
            }
            float acc[8] = {a01.x, a01.y, a23.x, a23.y, a45.x, a45.y, a67.x, a67.y};
#pragma unroll
            for (int k = 0; k < 8; ++k)
                acc[k] += __shfl_xor(acc[k], 8);

            // self-loop + scale + bias + relu
            uint4 sq = *(const uint4*)&g1[(size_t)d * 32 + fp * 4];
            float dvd = rsqrtf((float)deg[d] + 1.0f);
            acc[0] += BF_LO(sq.x) * dvd; acc[1] += BF_HI(sq.x) * dvd;
            acc[2] += BF_LO(sq.y) * dvd; acc[3] += BF_HI(sq.y) * dvd;
            acc[4] += BF_LO(sq.z) * dvd; acc[5] += BF_HI(sq.z) * dvd;
            acc[6] += BF_LO(sq.w) * dvd; acc[7] += BF_HI(sq.w) * dvd;
            float4 bb0 = ((const float4*)b1)[fp * 2];
            float4 bb1 = ((const float4*)b1)[fp * 2 + 1];
            float v0 = fmaxf(dvd * acc[0] + bb0.x, 0.f);
            float v1 = fmaxf(dvd * acc[1] + bb0.y, 0.f);
            float v2 = fmaxf(dvd * acc[2] + bb0.z, 0.f);
            float v3 = fmaxf(dvd * acc[3] + bb0.w, 0.f);
            float v4 = fmaxf(dvd * acc[4] + bb1.x, 0.f);
            float v5 = fmaxf(dvd * acc[5] + bb1.y, 0.f);
            float v6 = fmaxf(dvd * acc[6] + bb1.z, 0.f);
            float v7 = fmaxf(dvd * acc[7] + bb1.w, 0.f);
            if (grp == 0) {
                t1s[lt * 33 + fp * 4 + 0] = pack_bf16x2(v0, v1);
                t1s[lt * 33 + fp * 4 + 1] = pack_bf16x2(v2, v3);
                t1s[lt * 33 + fp * 4 + 2] = pack_bf16x2(v4, v5);
                t1s[lt * 33 + fp * 4 + 3] = pack_bf16x2(v6, v7);
            }
        }
        __syncthreads();

        // phase 5: gemm2 tail. wave -> col tile cw; row tiles rt = (wave>>1)+4j.
        // W2 split bf16-hi + bf16-residual (fp32-effective precision).
        union { unsigned u[4]; short8v s; } bh0, bh1, bl0, bl1;
#pragma unroll
        for (int jp = 0; jp < 4; ++jp) {
            int k0 = quad * 8 + jp * 2;
            float f0 = W2[(size_t)k0 * OUT_DIM + col];
            float f1 = W2[(size_t)(k0 + 1) * OUT_DIM + col];
            float f2 = W2[(size_t)(k0 + 32) * OUT_DIM + col];
            float f3 = W2[(size_t)(k0 + 33) * OUT_DIM + col];
            unsigned short h0 = f2bf(f0), h1 = f2bf(f1);
            unsigned short h2 = f2bf(f2), h3 = f2bf(f3);
            bh0.u[jp] = (unsigned)h0 | ((unsigned)h1 << 16);
            bh1.u[jp] = (unsigned)h2 | ((unsigned)h3 << 16);
            float r0 = f0 - __uint_as_float((unsigned)h0 << 16);
            float r1 = f1 - __uint_as_float((unsigned)h1 << 16);
            float r2 = f2 - __uint_as_float((unsigned)h2 << 16);
            float r3 = f3 - __uint_as_float((unsigned)h3 << 16);
            bl0.u[jp] = pack_bf16x2(r0, r1);
            bl1.u[jp] = pack_bf16x2(r2, r3);
        }
#pragma unroll
        for (int j = 0; j < 2; ++j) {
            int rt = (wave >> 1) + 4 * j;  // 0..7 row tiles of this half
            union { unsigned u[4]; short8v s; } af0, af1;
#pragma unroll
            for (int jp = 0; jp < 4; ++jp) {
                af0.u[jp] = t1s[(rt * 16 + n16) * 33 + jp + quad * 4];
                af1.u[jp] = t1s[(rt * 16 + n16) * 33 + 16 + jp + quad * 4];
            }
            float4v acc2 = {0.f, 0.f, 0.f, 0.f};
            acc2 = __builtin_amdgcn_mfma_f32_16x16x32_bf16(af0.s, bh0.s, acc2, 0, 0, 0);
            acc2 = __builtin_amdgcn_mfma_f32_16x16x32_bf16(af1.s, bh1.s, acc2, 0, 0, 0);
            acc2 = __builtin_amdgcn_mfma_f32_16x16x32_bf16(af0.s, bl0.s, acc2, 0, 0, 0);
            acc2 = __builtin_amdgcn_mfma_f32_16x16x32_bf16(af1.s, bl1.s, acc2, 0, 0, 0);
#pragma unroll
            for (int reg = 0; reg < 4; ++reg) {
                int row = (bkt << BSHIFT) + half * 128 + rt * 16 + quad * 4 + reg;
                if (row < N) {
                    float dvr = rsqrtf((float)deg[row] + 1.0f);
                    g2s[(size_t)row * 32 + col] = f2bf(acc2[reg] * dvr);
                }
            }
        }
        __syncthreads();  // t1s reused by next half
    }
}

// ---------------------------------------------------------------- agg layer 2 (deg-based scale)
__global__ __launch_bounds__(128) void k_agg2(const unsigned* __restrict__ g2,
                                              const uint2* __restrict__ rowptr2,
                                              const int* __restrict__ colidx,
                                              const int* __restrict__ deg,
                                              const float* __restrict__ b2,
                                              float* __restrict__ out, int N) {
    int t = threadIdx.x;
    int lane = t & 63;
    int o = lane >> 3, ol = lane & 7;
    int grp = ol >> 2, fp = ol & 3;
    int dd = blockIdx.x * 16 + (t >> 6) * 8 + o;
    bool live = dd < N;
    int d = live ? dd : N - 1;

    uint2 be = rowptr2[d];
    v2f a01 = {0.f, 0.f}, a23 = {0.f, 0.f}, a45 = {0.f, 0.f}, a67 = {0.f, 0.f};
#define ACC8V(qv)                                    \
    do {                                             \
        a01 += bfpair((qv).x); a23 += bfpair((qv).y);\
        a45 += bfpair((qv).z); a67 += bfpair((qv).w);\
    } while (0)
    int e = (int)be.x, end = (int)be.y;
    for (; e + 4 <= end; e += 4) {
        int s0 = colidx[e + grp];
        int s1 = colidx[e + 2 + grp];
        uint4 q0 = *(const uint4*)&g2[(size_t)s0 * 16 + fp * 4];
        uint4 q1 = *(const uint4*)&g2[(size_t)s1 * 16 + fp * 4];
        ACC8V(q0);
        ACC8V(q1);
    }
    for (; e + 2 <= end; e += 2) {
        int s = colidx[e + grp];
        uint4 qv = *(const uint4*)&g2[(size_t)s * 16 + fp * 4];
        ACC8V(qv);
    }
    if (e < end) {  // 1 edge left: grp 0 only
        int s = colidx[e];
        uint4 qv = *(const uint4*)&g2[(size_t)s * 16 + fp * 4];
        if (grp == 0) ACC8V(qv);
    }
#undef ACC8V
    float acc[8] = {a01.x, a01.y, a23.x, a23.y, a45.x, a45.y, a67.x, a67.y};
#pragma unroll
    for (int i = 0; i < 8; ++i)
        acc[i] += __shfl_xor(acc[i], 4);
    // self-loop + epilogue (per octet)
    uint4 sq = *(const uint4*)&g2[(size_t)d * 16 + fp * 4];
    ACC8(sq);
    float dv = rsqrtf((float)deg[d] + 1.0f);
    float4 bb0 = ((const float4*)b2)[fp * 2];
    float4 bb1 = ((const float4*)b2)[fp * 2 + 1];
    if (live && grp == 0) {
        float4 r0, r1;
        r0.x = dv * acc[0] + bb0.x; r0.y = dv * acc[1] + bb0.y;
        r0.z = dv * acc[2] + bb0.z; r0.w = dv * acc[3] + bb0.w;
        r1.x = dv * acc[4] + bb1.x; r1.y = dv * acc[5] + bb1.y;
        r1.z = dv * acc[6] + bb1.z; r1.w = dv * acc[7] + bb1.w;
        *(float4*)&out[(size_t)dd * OUT_DIM + fp * 8] = r0;
        *(float4*)&out[(size_t)dd * OUT_DIM + fp * 8 + 4] = r1;
    }
}

// ---------------------------------------------------------------- launch
extern "C" void kernel_launch(void* const* d_in, const int* in_sizes, int n_in,
                              void* d_out, int out_size, void* d_ws, size_t ws_size,
                              hipStream_t stream) {
    const float* x  = (const float*)d_in[0];
    const int*   ei = (const int*)d_in[1];
    const float* W1 = (const float*)d_in[2];
    const float* b1 = (const float*)d_in[3];
    const float* W2 = (const float*)d_in[4];
    const float* b2 = (const float*)d_in[5];
    float* out = (float*)d_out;

    const int N = in_sizes[0] / IN_DIM;
    const int E = in_sizes[1] / 2;
    const int* src = ei;
    const int* dst = ei + E;

    const int B   = (N + BSIZE - 1) / BSIZE;          // buckets
    const int nPB = (E + PEB - 1) / PEB;              // partition blocks
    const int nGB = (N + 31) / 32;                    // gemm1 blocks
    const size_t SLOTS = (size_t)B << CAPSHIFT;       // segmented edge slots

    char* p = (char*)d_ws;
    auto alloc = [&](size_t bytes) -> void* {
        void* r = (void*)p;
        p += (bytes + 255) & ~(size_t)255;
        return r;
    };
    int*      bfill   = (int*)alloc((size_t)B * 4);
    int*      deg     = (int*)alloc((size_t)N * 4);
    unsigned* packed  = (unsigned*)alloc(SLOTS * 4);
    int*      colidx  = (int*)alloc(SLOTS * 4);
    uint2*    rowptr2 = (uint2*)alloc((size_t)N * 8);
    unsigned* g1b     = (unsigned*)alloc((size_t)N * 32 * 4);  // bf16x2 x 32/row
    unsigned* g2b     = (unsigned*)alloc((size_t)N * 16 * 4);  // bf16x2 x 16/row

    // zero bfill + deg in one contiguous memset
    size_t zbytes = (size_t)((char*)(deg + N) - (char*)bfill);
    hipMemsetAsync(bfill, 0, zbytes, stream);

    k_part_gemm1<<<nPB + nGB, PTHREADS, 0, stream>>>(src, dst, E, bfill, deg, packed, B,
                                                     nPB, x, W1, g1b, N);
    k_bktagg<<<B, 512, 0, stream>>>(packed, bfill, g1b, deg, b1, W2, colidx, rowptr2,
                                    (unsigned short*)g2b, N);
    k_agg2<<<(N + 15) / 16, 128, 0, stream>>>(g2b, rowptr2, colidx, deg, b2, out, N);
}

// Round 4
// 199.613 us; speedup vs baseline: 1.2513x; 1.2513x over previous
//
#include <hip/hip_runtime.h>
#include <hip/hip_bf16.h>

// 2-layer GCN (PyG GCNConv) on MI355X.
// R22 = R21 resubmitted (previous bench died on container infra, not kernel).
// R21: revert R20's deg-global-atomics (cross-XCD L2 line thrash: WRITE_SIZE
// 26->70MB, partition 43->90us). Back to R19 structure: csrfill computes dinv
// from bucket-local LDS counts. New: agg1g2/agg2 edge loops unrolled to 8
// edges/iter with batched colidx->dinv/row loads (2x memory-level parallelism
// in the latency-bound gather loops). gemm1 keeps x-loads-first, LDS stride
// reverted to 66 (68 tripled bank conflicts in R20). Partition keeps src
// prefetch. Pipeline: memset -> [partition | gemm1] -> csrfill -> agg1+gemm2
// -> agg2.

#define IN_DIM 128
#define HID_DIM 64
#define OUT_DIM 32
#define BSHIFT 8
#define BSIZE 256
#define BMASK 255
#define PEB 8192      // edges per partition block
#define PTHREADS 512
#define CAPSHIFT 13   // 8192 slots per bucket segment (expected max ~4500)

typedef __attribute__((ext_vector_type(2))) float v2f;
typedef __attribute__((ext_vector_type(8))) short short8v;
typedef __attribute__((ext_vector_type(4))) float float4v;

__device__ inline unsigned pack_bf16x2(float a, float b) {
    unsigned ua = __float_as_uint(a), ub = __float_as_uint(b);
    unsigned ra = (ua + 0x7fffu + ((ua >> 16) & 1u)) >> 16;        // RNE
    unsigned rb = (ub + 0x7fffu + ((ub >> 16) & 1u)) & 0xffff0000u;
    return (ra & 0xffffu) | rb;
}
__device__ inline unsigned short f2bf(float f) {
    unsigned u = __float_as_uint(f);
    return (unsigned short)((u + 0x7fffu + ((u >> 16) & 1u)) >> 16);
}
#define BF_LO(w) __uint_as_float((w) << 16)
#define BF_HI(w) __uint_as_float((w) & 0xffff0000u)

__device__ inline v2f bfpair(unsigned u) {
    v2f r;
    r.x = __uint_as_float(u << 16);
    r.y = __uint_as_float(u & 0xffff0000u);
    return r;
}
// scaled accumulate of a bf16x2 word
__device__ inline void accp(v2f& a, unsigned u, float dv) {
    a.x += BF_LO(u) * dv;
    a.y += BF_HI(u) * dv;
}

#define ACC8(q)                                         \
    do {                                                \
        acc[0] += BF_LO((q).x); acc[1] += BF_HI((q).x); \
        acc[2] += BF_LO((q).y); acc[3] += BF_HI((q).y); \
        acc[4] += BF_LO((q).z); acc[5] += BF_HI((q).z); \
        acc[6] += BF_LO((q).w); acc[7] += BF_HI((q).w); \
    } while (0)

// ---------------------------------------------------------------- K1: fused partition + gemm1
// blocks [0, nPB): partition. blocks [nPB, ...): gemm1, 512 threads = 8 waves,
// 32 rows/block. g1b = bf16(x @ W1) -- UNSCALED (dinv applied per edge in agg1).
__global__ __launch_bounds__(PTHREADS) void k_part_gemm1(
        const int* __restrict__ src, const int* __restrict__ dst, int E,
        int* __restrict__ bfill, unsigned* __restrict__ packed, int B, int nPB,
        const float* __restrict__ x, const float* __restrict__ W,
        unsigned* __restrict__ g1b, int N) {
    __shared__ int cnt[512];
    __shared__ int off[512];
    __shared__ unsigned xs[32 * 66];  // 8.4 KB
    int t = threadIdx.x;

    if (blockIdx.x < nPB) {
        // ---------------- partition body ----------------
        cnt[t] = 0;
        __syncthreads();
        int base = blockIdx.x * PEB;
        int dv[PEB / PTHREADS];
        int sv[PEB / PTHREADS];
#pragma unroll
        for (int i = 0; i < PEB / PTHREADS; ++i) {
            int e = base + i * PTHREADS + t;
            bool ok = e < E;
            dv[i] = ok ? dst[e] : -1;
            sv[i] = ok ? src[e] : 0;  // prefetch: kills phase-3 dependent load
            if (dv[i] >= 0) atomicAdd(&cnt[dv[i] >> BSHIFT], 1);
        }
        __syncthreads();
        for (int b = t; b < B; b += PTHREADS) {
            int c = cnt[b];
            int o = c ? atomicAdd(&bfill[b], c) : 0;
            off[b] = (b << CAPSHIFT) + o;
        }
        __syncthreads();
#pragma unroll
        for (int i = 0; i < PEB / PTHREADS; ++i) {
            int d = dv[i];
            if (d >= 0) {
                int slot = atomicAdd(&off[d >> BSHIFT], 1);
                packed[slot] = ((unsigned)sv[i] << BSHIFT) | (unsigned)(d & BMASK);
            }
        }
    } else {
        // ---------------- gemm1 body ----------------
        int row0 = (blockIdx.x - nPB) * 32;
        int w = t >> 6, lane = t & 63;
        int rg = w >> 2, wv = w & 3;  // row-group, col-wave
        int quad = lane >> 4, m = lane & 15;
        int ncol = wv * 16 + m;

        // x loads FIRST (HBM latency overlaps W fragment build)
        float4 xf[2];
#pragma unroll
        for (int i = 0; i < 2; ++i) {
            int idx = t + 512 * i;
            int r = idx >> 5, c4 = idx & 31;
            int grow = row0 + r;
            xf[i] = make_float4(0.f, 0.f, 0.f, 0.f);
            if (grow < N) xf[i] = ((const float4*)x)[(size_t)grow * 32 + c4];
        }

        // B-frags: bfrag[kt] element j = W[(kt*32 + quad*8 + j)*64 + ncol]
        union { unsigned u[4]; short8v s; } bf[4];
#pragma unroll
        for (int kt = 0; kt < 4; ++kt) {
#pragma unroll
            for (int jp = 0; jp < 4; ++jp) {
                int k0 = kt * 32 + quad * 8 + jp * 2;
                float f0 = W[(size_t)k0 * HID_DIM + ncol];
                float f1 = W[(size_t)(k0 + 1) * HID_DIM + ncol];
                bf[kt].u[jp] = pack_bf16x2(f0, f1);
            }
        }

        // stage x tile (32 rows x 128 fp32 -> bf16x2)
#pragma unroll
        for (int i = 0; i < 2; ++i) {
            int idx = t + 512 * i;
            int r = idx >> 5, c4 = idx & 31;
            xs[r * 66 + c4 * 2]     = pack_bf16x2(xf[i].x, xf[i].y);
            xs[r * 66 + c4 * 2 + 1] = pack_bf16x2(xf[i].z, xf[i].w);
        }
        __syncthreads();

        float4v acc = {0.f, 0.f, 0.f, 0.f};
#pragma unroll
        for (int kt = 0; kt < 4; ++kt) {
            union { unsigned u[4]; short8v s; } af;
            const unsigned* ap = &xs[(rg * 16 + m) * 66 + kt * 16 + quad * 4];
            af.u[0] = ap[0]; af.u[1] = ap[1]; af.u[2] = ap[2]; af.u[3] = ap[3];
            acc = __builtin_amdgcn_mfma_f32_16x16x32_bf16(af.s, bf[kt].s, acc, 0, 0, 0);
        }

        unsigned short* g1s = (unsigned short*)g1b;
#pragma unroll
        for (int reg = 0; reg < 4; ++reg) {
            int r = row0 + rg * 16 + quad * 4 + reg;
            if (r < N) g1s[(size_t)r * HID_DIM + ncol] = f2bf(acc[reg]);
        }
    }
}

// ---------------------------------------------------------------- per-bucket CSR build
__global__ __launch_bounds__(512) void k_csrfill(const unsigned* __restrict__ packed,
                                                 const int* __restrict__ bfill,
                                                 int* __restrict__ colidx,
                                                 uint2* __restrict__ rowptr2,
                                                 float* __restrict__ dinv,
                                                 int N, int B) {
    __shared__ int ldeg[256];
    __shared__ int lscan[256];
    __shared__ int sexc[256];
    __shared__ int lfill[256];
    int t = threadIdx.x, bkt = blockIdx.x;
    int base = bkt << CAPSHIFT;
    int end  = base + bfill[bkt];
    if (t < 256) ldeg[t] = 0;
    __syncthreads();
    for (int e = base + t; e < end; e += 512)
        atomicAdd(&ldeg[packed[e] & BMASK], 1);
    __syncthreads();
    int v = (t < 256) ? ldeg[t] : 0;
    if (t < 256) lscan[t] = v;
    __syncthreads();
    for (int off = 1; off < 256; off <<= 1) {
        int x = (t < 256 && t >= off) ? lscan[t - off] : 0;
        __syncthreads();
        if (t < 256) lscan[t] += x;
        __syncthreads();
    }
    if (t < 256) {
        int exc = lscan[t] - v;
        sexc[t] = exc;
        lfill[t] = 0;
        int node = (bkt << BSHIFT) + t;
        if (node < N) {
            rowptr2[node] = make_uint2((unsigned)(base + exc), (unsigned)(base + exc + v));
            dinv[node] = rsqrtf((float)v + 1.0f);
        }
    }
    __syncthreads();
    for (int e = base + t; e < end; e += 512) {
        unsigned w = packed[e];
        int ld = w & BMASK;
        int pos = base + sexc[ld] + atomicAdd(&lfill[ld], 1);
        colidx[pos] = (int)(w >> BSHIFT);
    }
}

// ---------------------------------------------------------------- K3: fused agg1 + gemm2
// 256 threads = 4 waves; node per 16-lane quarter -> 16 nodes/block.
// Edge loop: 8-edge unrolled pipeline (4 colidx -> 4 dinv + 4 rows in flight).
__global__ __launch_bounds__(256) void k_agg1g2(const unsigned* __restrict__ g1,
                                                const uint2* __restrict__ rowptr2,
                                                const int* __restrict__ colidx,
                                                const float* __restrict__ dinv,
                                                const float* __restrict__ b1,
                                                const float* __restrict__ W2,
                                                unsigned short* __restrict__ g2s, int N) {
    __shared__ unsigned t1s[16 * 33];  // 16 nodes x 32 bf16x2, stride 33
    int t = threadIdx.x;
    int wave = t >> 6, lane = t & 63;
    int q = lane >> 4, ql = lane & 15;
    int grp = ql >> 3, fp = ql & 7;
    int nl = wave * 4 + q;  // node-local 0..15
    int dd = blockIdx.x * 16 + nl;
    bool live = dd < N;
    int d = live ? dd : N - 1;

    uint2 be = rowptr2[d];
    v2f a01 = {0.f, 0.f}, a23 = {0.f, 0.f}, a45 = {0.f, 0.f}, a67 = {0.f, 0.f};
#define ACCR(qv, dv)                                     \
    do {                                                 \
        accp(a01, (qv).x, dv); accp(a23, (qv).y, dv);    \
        accp(a45, (qv).z, dv); accp(a67, (qv).w, dv);    \
    } while (0)
    int e = (int)be.x, end = (int)be.y;
    for (; e + 8 <= end; e += 8) {
        int s0 = colidx[e + grp];
        int s1 = colidx[e + 2 + grp];
        int s2 = colidx[e + 4 + grp];
        int s3 = colidx[e + 6 + grp];
        float dv0 = dinv[s0], dv1 = dinv[s1], dv2 = dinv[s2], dv3 = dinv[s3];
        uint4 q0 = *(const uint4*)&g1[(size_t)s0 * 32 + fp * 4];
        uint4 q1 = *(const uint4*)&g1[(size_t)s1 * 32 + fp * 4];
        uint4 q2 = *(const uint4*)&g1[(size_t)s2 * 32 + fp * 4];
        uint4 q3 = *(const uint4*)&g1[(size_t)s3 * 32 + fp * 4];
        ACCR(q0, dv0); ACCR(q1, dv1); ACCR(q2, dv2); ACCR(q3, dv3);
    }
    for (; e + 4 <= end; e += 4) {
        int s0 = colidx[e + grp];
        int s1 = colidx[e + 2 + grp];
        float dv0 = dinv[s0], dv1 = dinv[s1];
        uint4 q0 = *(const uint4*)&g1[(size_t)s0 * 32 + fp * 4];
        uint4 q1 = *(const uint4*)&g1[(size_t)s1 * 32 + fp * 4];
        ACCR(q0, dv0); ACCR(q1, dv1);
    }
    for (; e + 2 <= end; e += 2) {
        int s = colidx[e + grp];
        float dv = dinv[s];
        uint4 qv = *(const uint4*)&g1[(size_t)s * 32 + fp * 4];
        ACCR(qv, dv);
    }
    if (e < end) {  // 1 edge left: grp 0 only
        int s = colidx[e];
        float dv = dinv[s];
        uint4 qv = *(const uint4*)&g1[(size_t)s * 32 + fp * 4];
        if (grp == 0) ACCR(qv, dv);
    }
#undef ACCR
    float acc[8] = {a01.x, a01.y, a23.x, a23.y, a45.x, a45.y, a67.x, a67.y};
#pragma unroll
    for (int i = 0; i < 8; ++i)
        acc[i] += __shfl_xor(acc[i], 8);

    // self-loop (coef dinv_d) + scale + bias + relu
    uint4 sq = *(const uint4*)&g1[(size_t)d * 32 + fp * 4];
    float dvd = dinv[d];
    acc[0] += BF_LO(sq.x) * dvd; acc[1] += BF_HI(sq.x) * dvd;
    acc[2] += BF_LO(sq.y) * dvd; acc[3] += BF_HI(sq.y) * dvd;
    acc[4] += BF_LO(sq.z) * dvd; acc[5] += BF_HI(sq.z) * dvd;
    acc[6] += BF_LO(sq.w) * dvd; acc[7] += BF_HI(sq.w) * dvd;
    float4 bb0 = ((const float4*)b1)[fp * 2];
    float4 bb1 = ((const float4*)b1)[fp * 2 + 1];
    float v0 = fmaxf(dvd * acc[0] + bb0.x, 0.f);
    float v1 = fmaxf(dvd * acc[1] + bb0.y, 0.f);
    float v2 = fmaxf(dvd * acc[2] + bb0.z, 0.f);
    float v3 = fmaxf(dvd * acc[3] + bb0.w, 0.f);
    float v4 = fmaxf(dvd * acc[4] + bb1.x, 0.f);
    float v5 = fmaxf(dvd * acc[5] + bb1.y, 0.f);
    float v6 = fmaxf(dvd * acc[6] + bb1.z, 0.f);
    float v7 = fmaxf(dvd * acc[7] + bb1.w, 0.f);
    if (grp == 0) {
        t1s[nl * 33 + fp * 4 + 0] = pack_bf16x2(v0, v1);
        t1s[nl * 33 + fp * 4 + 1] = pack_bf16x2(v2, v3);
        t1s[nl * 33 + fp * 4 + 2] = pack_bf16x2(v4, v5);
        t1s[nl * 33 + fp * 4 + 3] = pack_bf16x2(v6, v7);
    }
    __syncthreads();

    // ---------------- gemm2 tail: waves 0-1 -> col tiles 0-15 / 16-31 ----------------
    if (wave < 2) {
        int quad = lane >> 4, n = lane & 15;
        int col = (wave << 4) + n;
        union { unsigned u[4]; short8v s; } af0, af1, bh0, bh1, bl0, bl1;
#pragma unroll
        for (int jp = 0; jp < 4; ++jp) {
            int k0 = quad * 8 + jp * 2;
            float f0 = W2[(size_t)k0 * OUT_DIM + col];
            float f1 = W2[(size_t)(k0 + 1) * OUT_DIM + col];
            float f2 = W2[(size_t)(k0 + 32) * OUT_DIM + col];
            float f3 = W2[(size_t)(k0 + 33) * OUT_DIM + col];
            unsigned short h0 = f2bf(f0), h1 = f2bf(f1);
            unsigned short h2 = f2bf(f2), h3 = f2bf(f3);
            bh0.u[jp] = (unsigned)h0 | ((unsigned)h1 << 16);
            bh1.u[jp] = (unsigned)h2 | ((unsigned)h3 << 16);
            float r0 = f0 - __uint_as_float((unsigned)h0 << 16);
            float r1 = f1 - __uint_as_float((unsigned)h1 << 16);
            float r2 = f2 - __uint_as_float((unsigned)h2 << 16);
            float r3 = f3 - __uint_as_float((unsigned)h3 << 16);
            bl0.u[jp] = pack_bf16x2(r0, r1);
            bl1.u[jp] = pack_bf16x2(r2, r3);
            af0.u[jp] = t1s[n * 33 + quad * 4 + jp];
            af1.u[jp] = t1s[n * 33 + 16 + quad * 4 + jp];
        }
        float4v acc2 = {0.f, 0.f, 0.f, 0.f};
        acc2 = __builtin_amdgcn_mfma_f32_16x16x32_bf16(af0.s, bh0.s, acc2, 0, 0, 0);
        acc2 = __builtin_amdgcn_mfma_f32_16x16x32_bf16(af1.s, bh1.s, acc2, 0, 0, 0);
        acc2 = __builtin_amdgcn_mfma_f32_16x16x32_bf16(af0.s, bl0.s, acc2, 0, 0, 0);
        acc2 = __builtin_amdgcn_mfma_f32_16x16x32_bf16(af1.s, bl1.s, acc2, 0, 0, 0);
#pragma unroll
        for (int reg = 0; reg < 4; ++reg) {
            int row = blockIdx.x * 16 + quad * 4 + reg;
            if (row < N) g2s[(size_t)row * 32 + col] = f2bf(acc2[reg] * dinv[row]);
        }
    }
}

// ---------------------------------------------------------------- agg layer 2
__global__ __launch_bounds__(128) void k_agg2(const unsigned* __restrict__ g2,
                                              const uint2* __restrict__ rowptr2,
                                              const int* __restrict__ colidx,
                                              const float* __restrict__ dinv,
                                              const float* __restrict__ b2,
                                              float* __restrict__ out, int N) {
    int t = threadIdx.x;
    int lane = t & 63;
    int o = lane >> 3, ol = lane & 7;
    int grp = ol >> 2, fp = ol & 3;
    int dd = blockIdx.x * 16 + (t >> 6) * 8 + o;
    bool live = dd < N;
    int d = live ? dd : N - 1;

    uint2 be = rowptr2[d];
    v2f a01 = {0.f, 0.f}, a23 = {0.f, 0.f}, a45 = {0.f, 0.f}, a67 = {0.f, 0.f};
#define ACC8V(qv)                                    \
    do {                                             \
        a01 += bfpair((qv).x); a23 += bfpair((qv).y);\
        a45 += bfpair((qv).z); a67 += bfpair((qv).w);\
    } while (0)
    int e = (int)be.x, end = (int)be.y;
    for (; e + 8 <= end; e += 8) {
        int s0 = colidx[e + grp];
        int s1 = colidx[e + 2 + grp];
        int s2 = colidx[e + 4 + grp];
        int s3 = colidx[e + 6 + grp];
        uint4 q0 = *(const uint4*)&g2[(size_t)s0 * 16 + fp * 4];
        uint4 q1 = *(const uint4*)&g2[(size_t)s1 * 16 + fp * 4];
        uint4 q2 = *(const uint4*)&g2[(size_t)s2 * 16 + fp * 4];
        uint4 q3 = *(const uint4*)&g2[(size_t)s3 * 16 + fp * 4];
        ACC8V(q0); ACC8V(q1); ACC8V(q2); ACC8V(q3);
    }
    for (; e + 4 <= end; e += 4) {
        int s0 = colidx[e + grp];
        int s1 = colidx[e + 2 + grp];
        uint4 q0 = *(const uint4*)&g2[(size_t)s0 * 16 + fp * 4];
        uint4 q1 = *(const uint4*)&g2[(size_t)s1 * 16 + fp * 4];
        ACC8V(q0);
        ACC8V(q1);
    }
    for (; e + 2 <= end; e += 2) {
        int s = colidx[e + grp];
        uint4 qv = *(const uint4*)&g2[(size_t)s * 16 + fp * 4];
        ACC8V(qv);
    }
    if (e < end) {  // 1 edge left: grp 0 only
        int s = colidx[e];
        uint4 qv = *(const uint4*)&g2[(size_t)s * 16 + fp * 4];
        if (grp == 0) ACC8V(qv);
    }
#undef ACC8V
    float acc[8] = {a01.x, a01.y, a23.x, a23.y, a45.x, a45.y, a67.x, a67.y};
#pragma unroll
    for (int i = 0; i < 8; ++i)
        acc[i] += __shfl_xor(acc[i], 4);
    // self-loop + epilogue (per octet)
    uint4 sq = *(const uint4*)&g2[(size_t)d * 16 + fp * 4];
    ACC8(sq);
    float dv = dinv[d];
    float4 bb0 = ((const float4*)b2)[fp * 2];
    float4 bb1 = ((const float4*)b2)[fp * 2 + 1];
    if (live && grp == 0) {
        float4 r0, r1;
        r0.x = dv * acc[0] + bb0.x; r0.y = dv * acc[1] + bb0.y;
        r0.z = dv * acc[2] + bb0.z; r0.w = dv * acc[3] + bb0.w;
        r1.x = dv * acc[4] + bb1.x; r1.y = dv * acc[5] + bb1.y;
        r1.z = dv * acc[6] + bb1.z; r1.w = dv * acc[7] + bb1.w;
        *(float4*)&out[(size_t)dd * OUT_DIM + fp * 8] = r0;
        *(float4*)&out[(size_t)dd * OUT_DIM + fp * 8 + 4] = r1;
    }
}

// ---------------------------------------------------------------- launch
extern "C" void kernel_launch(void* const* d_in, const int* in_sizes, int n_in,
                              void* d_out, int out_size, void* d_ws, size_t ws_size,
                              hipStream_t stream) {
    const float* x  = (const float*)d_in[0];
    const int*   ei = (const int*)d_in[1];
    const float* W1 = (const float*)d_in[2];
    const float* b1 = (const float*)d_in[3];
    const float* W2 = (const float*)d_in[4];
    const float* b2 = (const float*)d_in[5];
    float* out = (float*)d_out;

    const int N = in_sizes[0] / IN_DIM;
    const int E = in_sizes[1] / 2;
    const int* src = ei;
    const int* dst = ei + E;

    const int B   = (N + BSIZE - 1) / BSIZE;          // buckets
    const int nPB = (E + PEB - 1) / PEB;              // partition blocks
    const int nGB = (N + 31) / 32;                    // gemm1 blocks
    const size_t SLOTS = (size_t)B << CAPSHIFT;       // segmented edge slots

    char* p = (char*)d_ws;
    auto alloc = [&](size_t bytes) -> void* {
        void* r = (void*)p;
        p += (bytes + 255) & ~(size_t)255;
        return r;
    };
    int*      bfill   = (int*)alloc((size_t)B * 4);
    unsigned* packed  = (unsigned*)alloc(SLOTS * 4);
    int*      colidx  = (int*)alloc(SLOTS * 4);
    uint2*    rowptr2 = (uint2*)alloc((size_t)N * 8);
    float*    dinv    = (float*)alloc((size_t)N * 4);
    unsigned* g1b     = (unsigned*)alloc((size_t)N * 32 * 4);  // bf16x2 x 32/row
    unsigned* g2b     = (unsigned*)alloc((size_t)N * 16 * 4);  // bf16x2 x 16/row

    hipMemsetAsync(bfill, 0, (size_t)B * 4, stream);
    k_part_gemm1<<<nPB + nGB, PTHREADS, 0, stream>>>(src, dst, E, bfill, packed, B, nPB,
                                                     x, W1, g1b, N);
    k_csrfill<<<B, 512, 0, stream>>>(packed, bfill, colidx, rowptr2, dinv, N, B);
    k_agg1g2<<<(N + 15) / 16, 256, 0, stream>>>(g1b, rowptr2, colidx, dinv, b1, W2,
                                                (unsigned short*)g2b, N);
    k_agg2<<<(N + 15) / 16, 128, 0, stream>>>(g2b, rowptr2, colidx, dinv, b2, out, N);
}